// Round 3
// baseline (3915.310 us; speedup 1.0000x reference)
//
#include <hip/hip_runtime.h>
#include <cstddef>

// LSTM: N=64, T=512, D=512, H=512.
// gates[t] = [x_t | h_{t-1}] @ [Wx; Wh] + b  (K=1024, fp16 MFMA, fp32 accum)
// Persistent scan: 128 WGs x 256 thr, each WG owns 4 hidden units (16 gate
// cols). Cross-WG sync: per-WG monotonic flags (sc1), h published via sc1
// write-through stores, h READ via plain cached loads after a per-wave
// buffer_inv sc1 (agent-acquire; safe because the scan creates NO dirty L2
// lines - out stores are sc1 write-through too). LDS weights stored in
// fragment-linear order (conflict-free ds_read_b128).

typedef _Float16 half8 __attribute__((ext_vector_type(8)));
typedef float f32x4 __attribute__((ext_vector_type(4)));

#define NBATCH 64
#define TSTEPS 512
#define DIN    512
#define HID    512
#define NCOL   2048
#define SCAN_WGS 128

__device__ __forceinline__ float fast_sigmoid(float x) {
  return 1.0f / (1.0f + __expf(-x));
}
__device__ __forceinline__ float fast_tanh(float x) {
  return 1.0f - 2.0f / (__expf(2.0f * x) + 1.0f);
}

// one-time per launch: x -> fp16, h0 -> h ping buffer, reset flags
__global__ void lstm_prep(const float* __restrict__ x, const float* __restrict__ h0,
                          _Float16* __restrict__ xb, _Float16* __restrict__ hbuf,
                          unsigned* __restrict__ flags)
{
  size_t gid = (size_t)blockIdx.x * blockDim.x + threadIdx.x;
  size_t stride = (size_t)gridDim.x * blockDim.x;
  const size_t NX = (size_t)NBATCH * TSTEPS * DIN;
  for (size_t i = gid * 4; i < NX; i += stride * 4) {
    float4 v = *(const float4*)(x + i);
    xb[i + 0] = (_Float16)v.x;
    xb[i + 1] = (_Float16)v.y;
    xb[i + 2] = (_Float16)v.z;
    xb[i + 3] = (_Float16)v.w;
  }
  for (size_t i = gid; i < (size_t)NBATCH * HID; i += stride)
    hbuf[i] = (_Float16)h0[i];
  if (gid < SCAN_WGS) flags[gid] = 0u;
}

__global__ __launch_bounds__(256, 1) void lstm_scan(
    const _Float16* __restrict__ xb,   // [N*T][D] fp16
    const float* __restrict__ Wx,      // [D][4H]
    const float* __restrict__ Wh,      // [H][4H]
    const float* __restrict__ bias,    // [4H]
    _Float16* __restrict__ hbuf,       // [2][N][H] fp16 ping-pong
    float* __restrict__ out,           // [N][T][H] fp32
    unsigned* __restrict__ flags)      // [128] monotonic per-WG step counters
{
  // fragment-linear weight storage: WF[ks][lane] is the 16B B-fragment chunk
  // lane `lane` needs for K-slice ks (col = lane&15, k = ks*32+(lane>>4)*8+j)
  __shared__ half8 WxF[16][64];        // 16 KB
  __shared__ half8 WhF[16][64];        // 16 KB
  __shared__ float gl[NBATCH][17];     // gates staging
  __shared__ float cl[NBATCH][4];      // cell state (persistent)
  __shared__ float bl[16];             // bias slice

  const int wg   = blockIdx.x;         // owns hidden units wg*4..wg*4+3
  const int tid  = threadIdx.x;
  const int lane = tid & 63;
  const int wave = tid >> 6;           // m-tile (16 batch rows each)

  // ---- one-time: stage weight slices fp32->fp16 into LDS (fragment order)
  {
    const int gate = tid & 3;
    const int k0   = tid >> 2;         // 0..63
    _Float16* wx = (_Float16*)WxF;
    _Float16* wh = (_Float16*)WhF;
    for (int pass = 0; pass < 8; ++pass) {
      int k = k0 + pass * 64;
      float4 vx = *(const float4*)(Wx + (size_t)k * NCOL + gate * 512 + wg * 4);
      float4 vh = *(const float4*)(Wh + (size_t)k * NCOL + gate * 512 + wg * 4);
      // dest half-index: ks*512 + (g*16 + col)*8 + e ; ks=k>>5, g=(k>>3)&3, e=k&7
      int base = (k >> 5) * 512 + (((k >> 3) & 3) * 16 + gate * 4) * 8 + (k & 7);
      wx[base + 0 * 8] = (_Float16)vx.x;
      wx[base + 1 * 8] = (_Float16)vx.y;
      wx[base + 2 * 8] = (_Float16)vx.z;
      wx[base + 3 * 8] = (_Float16)vx.w;
      wh[base + 0 * 8] = (_Float16)vh.x;
      wh[base + 1 * 8] = (_Float16)vh.y;
      wh[base + 2 * 8] = (_Float16)vh.z;
      wh[base + 3 * 8] = (_Float16)vh.w;
    }
    if (tid < 16) bl[tid] = bias[(tid >> 2) * 512 + wg * 4 + (tid & 3)];
    for (int i = tid; i < NBATCH * 4; i += 256) cl[i >> 2][i & 3] = 0.0f;
  }
  __syncthreads();

  // MFMA 16x16x32 fragment indices (A: row=lane&15, k=(lane>>4)*8+j;
  //  D: col=lane&15, row=(lane>>4)*4+j)
  const int fr = lane & 15;
  const int fk = (lane >> 4) * 8;
  const int mrow = wave * 16 + fr;
  const int n_ep = tid >> 2;
  const int hj_ep = tid & 3;
  const size_t out_col = (size_t)wg * 4 + hj_ep;

  // preload x fragments for t=0
  half8 xa[16];
#pragma unroll
  for (int ks = 0; ks < 16; ++ks)
    xa[ks] = *(const half8*)(xb + ((size_t)mrow * TSTEPS + 0) * DIN + ks * 32 + fk);

  for (int t = 0; t < TSTEPS; ++t) {
    // ---- wait: all 128 WGs have published h-input for step t ----
    if (t > 0) {
      if (tid < 64) {
        const unsigned tgt = (unsigned)t;
        for (;;) {
          unsigned long long v = __hip_atomic_load(
              (const unsigned long long*)flags + tid,
              __ATOMIC_RELAXED, __HIP_MEMORY_SCOPE_AGENT);
          bool ok = ((unsigned)v >= tgt) && ((unsigned)(v >> 32) >= tgt);
          if (__all(ok)) break;
          __builtin_amdgcn_s_sleep(1);
        }
      }
      __syncthreads();
      // per-wave agent-acquire: drain own vmem, invalidate clean L1/L2.
      // Safe: this kernel leaves no dirty L2 lines (all stores sc1).
      asm volatile("s_waitcnt vmcnt(0)\n\tbuffer_inv sc1" ::: "memory");
      __builtin_amdgcn_sched_barrier(0);
    }

    // ---- h-fragment loads: plain cached (L2-shared within the XCD) ----
    const _Float16* hsrc = hbuf + (size_t)(t & 1) * (NBATCH * HID) + (size_t)mrow * HID;
    half8 ha[16];
#pragma unroll
    for (int ks = 0; ks < 16; ++ks)
      ha[ks] = *(const half8*)(hsrc + ks * 32 + fk);

    f32x4 a0 = {0.f, 0.f, 0.f, 0.f};
    f32x4 a1 = {0.f, 0.f, 0.f, 0.f};
    f32x4 a2 = {0.f, 0.f, 0.f, 0.f};
    f32x4 a3 = {0.f, 0.f, 0.f, 0.f};
#pragma unroll
    for (int ks = 0; ks < 16; ks += 4) {
      a0 = __builtin_amdgcn_mfma_f32_16x16x32_f16(xa[ks],     WxF[ks][lane],     a0, 0, 0, 0);
      a1 = __builtin_amdgcn_mfma_f32_16x16x32_f16(xa[ks + 1], WxF[ks + 1][lane], a1, 0, 0, 0);
      a2 = __builtin_amdgcn_mfma_f32_16x16x32_f16(xa[ks + 2], WxF[ks + 2][lane], a2, 0, 0, 0);
      a3 = __builtin_amdgcn_mfma_f32_16x16x32_f16(xa[ks + 3], WxF[ks + 3][lane], a3, 0, 0, 0);
    }
#pragma unroll
    for (int ks = 0; ks < 16; ks += 4) {
      a0 = __builtin_amdgcn_mfma_f32_16x16x32_f16(ha[ks],     WhF[ks][lane],     a0, 0, 0, 0);
      a1 = __builtin_amdgcn_mfma_f32_16x16x32_f16(ha[ks + 1], WhF[ks + 1][lane], a1, 0, 0, 0);
      a2 = __builtin_amdgcn_mfma_f32_16x16x32_f16(ha[ks + 2], WhF[ks + 2][lane], a2, 0, 0, 0);
      a3 = __builtin_amdgcn_mfma_f32_16x16x32_f16(ha[ks + 3], WhF[ks + 3][lane], a3, 0, 0, 0);
    }
    f32x4 acc = (a0 + a1) + (a2 + a3);

    // stage gates to LDS (D layout: col=lane&15, row=(lane>>4)*4+j)
    {
      int gr = wave * 16 + ((lane >> 4) << 2);
#pragma unroll
      for (int j = 0; j < 4; ++j) gl[gr + j][fr] = acc[j];
    }
    __syncthreads();

    // ---- epilogue: one (n, hidden-unit) cell per thread ----
    {
      float iv = gl[n_ep][0  + hj_ep] + bl[0  + hj_ep];
      float fv = gl[n_ep][4  + hj_ep] + bl[4  + hj_ep];
      float ov = gl[n_ep][8  + hj_ep] + bl[8  + hj_ep];
      float gv = gl[n_ep][12 + hj_ep] + bl[12 + hj_ep];
      float ig = fast_sigmoid(iv);
      float fg = fast_sigmoid(fv);
      float og = fast_sigmoid(ov);
      float gg = fast_tanh(gv);
      float c = fg * cl[n_ep][hj_ep] + ig * gg;
      cl[n_ep][hj_ep] = c;
      float hval = og * fast_tanh(c);

      // out store: sc1 write-through (no dirty L2 line -> buffer_inv safe)
      const float* outp = out + ((size_t)n_ep * TSTEPS + t) * HID + out_col;
      asm volatile("global_store_dword %0, %1, off sc1"
                   :: "v"(outp), "v"(hval) : "memory");

      // pack fp16 pair with partner lane (hj^1), publish sc1 write-through
      float hpart = __shfl_xor(hval, 1);
      if ((hj_ep & 1) == 0) {
        _Float16 lo = (_Float16)hval, hi = (_Float16)hpart;
        unsigned packed = (unsigned)__builtin_bit_cast(unsigned short, lo) |
                          ((unsigned)__builtin_bit_cast(unsigned short, hi) << 16);
        unsigned* dst = (unsigned*)(hbuf + (size_t)((t + 1) & 1) * (NBATCH * HID) +
                                    (size_t)n_ep * HID + wg * 4 + hj_ep);
        __hip_atomic_store(dst, packed, __ATOMIC_RELAXED, __HIP_MEMORY_SCOPE_AGENT);
      }
    }

    // ---- release: drain this wave's stores, then arrive ----
    asm volatile("s_waitcnt vmcnt(0)" ::: "memory");
    __syncthreads();                   // all waves' stores drained
    if (tid == 0)
      __hip_atomic_store(&flags[wg], (unsigned)(t + 1),
                         __ATOMIC_RELAXED, __HIP_MEMORY_SCOPE_AGENT);

    // prefetch x fragments for t+1; overlaps the next poll
    if (t + 1 < TSTEPS) {
#pragma unroll
      for (int ks = 0; ks < 16; ++ks)
        xa[ks] = *(const half8*)(xb + ((size_t)mrow * TSTEPS + (t + 1)) * DIN + ks * 32 + fk);
    }
  }
}

extern "C" void kernel_launch(void* const* d_in, const int* in_sizes, int n_in,
                              void* d_out, int out_size, void* d_ws, size_t ws_size,
                              hipStream_t stream) {
  const float* x  = (const float*)d_in[0];
  const float* h0 = (const float*)d_in[1];
  const float* Wx = (const float*)d_in[2];
  const float* Wh = (const float*)d_in[3];
  const float* b  = (const float*)d_in[4];
  float* out = (float*)d_out;

  char* ws = (char*)d_ws;
  _Float16* xb    = (_Float16*)ws;                           // 33,554,432 B
  _Float16* hbuf  = (_Float16*)(ws + 33554432);              //    131,072 B
  unsigned* flags = (unsigned*)(ws + 33554432 + 131072);     //        512 B

  lstm_prep<<<dim3(2048), dim3(256), 0, stream>>>(x, h0, xb, hbuf, flags);
  lstm_scan<<<dim3(SCAN_WGS), dim3(256), 0, stream>>>(xb, Wx, Wh, b, hbuf, out, flags);
}